// Round 5
// baseline (89.573 us; speedup 1.0000x reference)
//
#include <hip/hip_runtime.h>
#include <hip/hip_bf16.h>
#include <math.h>

// Chamfer distance via MFMA, fp16 quantized / fp32 accumulate.
// K-packing: A_row = (-2ax,-2ay,-2az, 1, sqa, 0,0,0), B_col = (bx,by,bz, sqb, 1, 0,0,0)
// => MFMA dot = sqa + sqb - 2 a.b = full squared distance (from quantized coords).
// R5 vs R4 (same two-sweep structure, pure register row-mins, no atomics):
//  - LDS stores the COMPLETE 16B B-fragment -> ds_read_b128 is the MFMA operand
//    (no per-iter packing movs, no pack stage between load and MFMA).
//  - explicit 1-iteration software pipeline on the two fragment loads.
//  - no forced waves/EU bound (avoid spills); part[] relaid row-major for reduce1.

typedef _Float16 half8    __attribute__((ext_vector_type(8)));
typedef float    floatx16 __attribute__((ext_vector_type(16)));

constexpr int CH    = 2048;      // B points per block chunk
constexpr int RT    = 2;         // row-tiles per wave
constexpr int WROWS = RT * 32;   // 64 rows per wave
constexpr int ROWS  = 4 * WROWS; // 256 rows per block
constexpr int BLK   = 256;

__global__ __launch_bounds__(BLK) void chamfer_sweep_kernel(
    const float* __restrict__ P1, const float* __restrict__ P2,
    float* __restrict__ part, int n1, int n2, int YC)
{
    __shared__ uint4 sB[CH];          // per point: f16x8 fragment (x,y,z,sqb,1,0,0,0)
    __shared__ float sRowMin[ROWS];

    const int dir  = blockIdx.z;
    const float* A = dir == 0 ? P1 : P2;
    const float* B = dir == 0 ? P2 : P1;
    const int nA   = dir == 0 ? n1 : n2;
    const int nB   = dir == 0 ? n2 : n1;
    float* pbase   = part + (dir == 0 ? 0 : (size_t)YC * n1);

    const int tid  = threadIdx.x;
    const int wave = tid >> 6;
    const int lane = tid & 63;
    const int n    = lane & 31;
    const int g    = lane >> 5;
    const bool g0  = (g == 0);

    // ---- stage B chunk as ready-to-use MFMA fragments ----
    const int bstart = blockIdx.y * CH;
    for (int i = tid; i < CH; i += BLK) {
        int j = bstart + i; if (j >= nB) j = nB - 1;   // dup last point: min-safe
        float bx = B[3*j], by = B[3*j+1], bz = B[3*j+2];
        _Float16 hx = (_Float16)bx, hy = (_Float16)by, hz = (_Float16)bz;
        float qx = (float)hx, qy = (float)hy, qz = (float)hz;
        _Float16 hw = (_Float16)(qx*qx + qy*qy + qz*qz);
        union { _Float16 h[8]; uint4 u; } p;
        p.h[0] = hx; p.h[1] = hy; p.h[2] = hz; p.h[3] = hw;
        p.h[4] = (_Float16)1.0f; p.h[5] = (_Float16)0.0f;
        p.h[6] = (_Float16)0.0f; p.h[7] = (_Float16)0.0f;
        sB[i] = p.u;
    }

    // ---- A fragments (RT row-tiles per wave); k>=5 and all g1 lanes are zero,
    //      so the B fragment's k=4..7 content only matters on g0 (where it's 1,0,0,0)
    const _Float16 h0 = (_Float16)0.0f;
    half8 af[RT];
#pragma unroll
    for (int t = 0; t < RT; ++t) {
        int row = blockIdx.x * ROWS + wave * WROWS + t * 32 + n;
        if (row >= nA) row = nA - 1;
        float ax = A[3*row], ay = A[3*row+1], az = A[3*row+2];
        _Float16 hax = (_Float16)ax, hay = (_Float16)ay, haz = (_Float16)az;
        float qx = (float)hax, qy = (float)hay, qz = (float)haz;
        _Float16 hs = (_Float16)(qx*qx + qy*qy + qz*qz);
        af[t][0] = g0 ? (_Float16)(-2.0f * qx) : h0;
        af[t][1] = g0 ? (_Float16)(-2.0f * qy) : h0;
        af[t][2] = g0 ? (_Float16)(-2.0f * qz) : h0;
        af[t][3] = g0 ? (_Float16)1.0f : h0;
        af[t][4] = g0 ? hs : h0;
        af[t][5] = h0; af[t][6] = h0; af[t][7] = h0;
    }

    __syncthreads();

    floatx16 rowmin[RT];
#pragma unroll
    for (int t = 0; t < RT; ++t)
#pragma unroll
        for (int r = 0; r < 16; ++r) rowmin[t][r] = 1e30f;
    const floatx16 zacc = {};

    // ---- main sweep: 2 col-tiles per iter, software-pipelined fragment loads ----
    constexpr int ITERS = CH / 64;
    const uint4* bp = sB + n;
    uint4 q0 = bp[0];
    uint4 q1 = bp[32];
#pragma unroll 2
    for (int bt = 0; bt < ITERS; ++bt) {
        union { uint4 u; half8 v; } b0, b1;
        b0.u = q0; b1.u = q1;
        int nx = (bt + 1) & (ITERS - 1);       // wraps on last iter (harmless reread)
        q0 = bp[nx * 64];
        q1 = bp[nx * 64 + 32];

        floatx16 d00 = __builtin_amdgcn_mfma_f32_32x32x16_f16(af[0], b0.v, zacc, 0, 0, 0);
        floatx16 d01 = __builtin_amdgcn_mfma_f32_32x32x16_f16(af[0], b1.v, zacc, 0, 0, 0);
        floatx16 d10 = __builtin_amdgcn_mfma_f32_32x32x16_f16(af[1], b0.v, zacc, 0, 0, 0);
        floatx16 d11 = __builtin_amdgcn_mfma_f32_32x32x16_f16(af[1], b1.v, zacc, 0, 0, 0);

#pragma unroll
        for (int r = 0; r < 16; ++r) {
            rowmin[0][r] = fminf(fminf(rowmin[0][r], d00[r]), d01[r]);  // v_min3
            rowmin[1][r] = fminf(fminf(rowmin[1][r], d10[r]), d11[r]);
        }
    }

    // ---- epilogue: reduce across the 32 cols (xor-shuffle within n-group) ----
#pragma unroll
    for (int mask = 1; mask <= 16; mask <<= 1) {
#pragma unroll
        for (int t = 0; t < RT; ++t)
#pragma unroll
            for (int r = 0; r < 16; ++r)
                rowmin[t][r] = fminf(rowmin[t][r], __shfl_xor(rowmin[t][r], mask));
    }
    if (n == 0) {
#pragma unroll
        for (int t = 0; t < RT; ++t)
#pragma unroll
            for (int r = 0; r < 16; ++r) {
                int rr = wave * WROWS + t * 32 + g * 4 + ((r & 3) + 8 * (r >> 2));
                sRowMin[rr] = rowmin[t][r];
            }
    }
    __syncthreads();

    {   // one partial slot per (dir,row,ychunk): part[row*YC + y] — no atomics
        int grow = blockIdx.x * ROWS + tid;   // ROWS == BLK
        if (grow < nA) pbase[(size_t)grow * YC + blockIdx.y] = sRowMin[tid];
    }
}

// Stage 1: per-row min over YC contiguous partials -> sqrt -> per-block sum
__global__ __launch_bounds__(256) void reduce1_kernel(
    const float* __restrict__ part, float* __restrict__ bsum,
    int n1, int n2, int YC)
{
    __shared__ float s[256];
    int r = blockIdx.x * 256 + threadIdx.x;
    float acc = 0.0f;
    int ntot = n1 + n2;
    if (r < ntot) {
        const float* p = part + (size_t)r * YC;   // rows of both dirs are contiguous
        float m = 1e30f;
        for (int y = 0; y < YC; ++y) m = fminf(m, p[y]);
        acc = sqrtf(fmaxf(m, 0.0f));
    }
    s[threadIdx.x] = acc;
    __syncthreads();
    for (int w = 128; w > 0; w >>= 1) {
        if (threadIdx.x < w) s[threadIdx.x] += s[threadIdx.x + w];
        __syncthreads();
    }
    if (threadIdx.x == 0) bsum[blockIdx.x] = s[0];
}

// Stage 2: sum the per-block sums -> out[0]
__global__ __launch_bounds__(256) void reduce2_kernel(
    const float* __restrict__ bsum, int nb, float* __restrict__ out)
{
    __shared__ float s[256];
    float acc = 0.0f;
    for (int i = threadIdx.x; i < nb; i += 256) acc += bsum[i];
    s[threadIdx.x] = acc;
    __syncthreads();
    for (int w = 128; w > 0; w >>= 1) {
        if (threadIdx.x < w) s[threadIdx.x] += s[threadIdx.x + w];
        __syncthreads();
    }
    if (threadIdx.x == 0) out[0] = s[0];
}

extern "C" void kernel_launch(void* const* d_in, const int* in_sizes, int n_in,
                              void* d_out, int out_size, void* d_ws, size_t ws_size,
                              hipStream_t stream) {
    const float* P1 = (const float*)d_in[0];
    const float* P2 = (const float*)d_in[1];
    const int n1 = in_sizes[0] / 3;   // 16384
    const int n2 = in_sizes[1] / 3;   // 16384
    const int nmax = (n1 > n2) ? n1 : n2;
    const int YC = (nmax + CH - 1) / CH;          // y-chunks (same grid both dirs)

    float* part = (float*)d_ws;                   // [(n1+n2) * YC] partial row-mins
    float* bsum = part + (size_t)YC * (n1 + n2);  // per-block sums
    float* out  = (float*)d_out;

    {   // two independent sweeps (z = direction), pure register row-mins
        dim3 grid((nmax + ROWS - 1) / ROWS, YC, 2);
        chamfer_sweep_kernel<<<grid, BLK, 0, stream>>>(P1, P2, part, n1, n2, YC);
    }
    int nb = (n1 + n2 + 255) / 256;
    reduce1_kernel<<<nb, 256, 0, stream>>>(part, bsum, n1, n2, YC);
    reduce2_kernel<<<1, 256, 0, stream>>>(bsum, nb, out);
}

// Round 6
// 80.680 us; speedup vs baseline: 1.1102x; 1.1102x over previous
//
#include <hip/hip_runtime.h>
#include <hip/hip_bf16.h>
#include <math.h>

// Chamfer distance via MFMA, fp16 quantized / fp32 accumulate.
// K-packing: A_row = (-2ax,-2ay,-2az, 1, sqa, 0,0,0), B_col = (bx,by,bz, sqb, 1, ...)
// => MFMA dot = sqa + sqb - 2 a.b = full squared distance (from quantized coords).
// R6 vs R4/R5: RT=1 (one 32-row tile per wave) to shrink the live register set
// (d-results 32 regs, rowmin 16, A-frag 4 -> ~80 VGPRs total) so we get ~6
// waves/SIMD of latency hiding for the MFMA->min dependency chain. Per-pair
// VALU cost unchanged (16 v_min3 per 2048 pairs). 8-byte LDS fragments (R4
// style), unroll 4 for load/MFMA pipelining, launch_bounds as spill guard only.

typedef _Float16 half8    __attribute__((ext_vector_type(8)));
typedef float    floatx16 __attribute__((ext_vector_type(16)));

constexpr int CH   = 2048;     // B points per block chunk
constexpr int ROWS = 128;      // 4 waves * 32 rows
constexpr int BLK  = 256;

__global__ __launch_bounds__(BLK, 4) void chamfer_sweep_kernel(
    const float* __restrict__ P1, const float* __restrict__ P2,
    float* __restrict__ part, int n1, int n2, int YC)
{
    __shared__ uint2 sB[CH];          // per point: f16x4 (x, y, z, sqb)
    __shared__ float sRowMin[ROWS];

    const int dir  = blockIdx.z;
    const float* A = dir == 0 ? P1 : P2;
    const float* B = dir == 0 ? P2 : P1;
    const int nA   = dir == 0 ? n1 : n2;
    const int nB   = dir == 0 ? n2 : n1;
    float* pbase   = part + (dir == 0 ? 0 : (size_t)YC * n1);

    const int tid  = threadIdx.x;
    const int wave = tid >> 6;
    const int lane = tid & 63;
    const int n    = lane & 31;
    const int g    = lane >> 5;
    const bool g0  = (g == 0);

    // ---- stage B chunk: f16-quantized coords + sqb (from quantized coords) ----
    const int bstart = blockIdx.y * CH;
    for (int i = tid; i < CH; i += BLK) {
        int j = bstart + i; if (j >= nB) j = nB - 1;   // dup last point: min-safe
        float bx = B[3*j], by = B[3*j+1], bz = B[3*j+2];
        _Float16 hx = (_Float16)bx, hy = (_Float16)by, hz = (_Float16)bz;
        float qx = (float)hx, qy = (float)hy, qz = (float)hz;
        _Float16 hw = (_Float16)(qx*qx + qy*qy + qz*qz);
        union { _Float16 h[4]; uint2 u; } p;
        p.h[0] = hx; p.h[1] = hy; p.h[2] = hz; p.h[3] = hw;
        sB[i] = p.u;
    }

    // ---- A fragment: ONE 32-row tile per wave; zeros in k>=5 and all of g1 ----
    const _Float16 h0 = (_Float16)0.0f;
    half8 af;
    {
        int row = blockIdx.x * ROWS + wave * 32 + n;
        if (row >= nA) row = nA - 1;
        float ax = A[3*row], ay = A[3*row+1], az = A[3*row+2];
        _Float16 hax = (_Float16)ax, hay = (_Float16)ay, haz = (_Float16)az;
        float qx = (float)hax, qy = (float)hay, qz = (float)haz;
        _Float16 hs = (_Float16)(qx*qx + qy*qy + qz*qz);
        af[0] = g0 ? (_Float16)(-2.0f * qx) : h0;
        af[1] = g0 ? (_Float16)(-2.0f * qy) : h0;
        af[2] = g0 ? (_Float16)(-2.0f * qz) : h0;
        af[3] = g0 ? (_Float16)1.0f : h0;
        af[4] = g0 ? hs : h0;
        af[5] = h0; af[6] = h0; af[7] = h0;
    }
    unsigned c2;   // packed (1.0h, 0h): B-fragment k=4..5 constant (g1 don't-care)
    { union { _Float16 h[2]; unsigned u; } q;
      q.h[0] = (_Float16)1.0f; q.h[1] = h0; c2 = q.u; }

    __syncthreads();

    floatx16 rowmin;
#pragma unroll
    for (int r = 0; r < 16; ++r) rowmin[r] = 1e30f;
    const floatx16 zacc = {};

    // ---- main sweep: 2 B col-tiles (64 points) per iteration, 2 MFMAs ----
#pragma unroll 4
    for (int bt = 0; bt < CH / 64; ++bt) {
        uint2 b0 = sB[bt * 64 + n];        // broadcast: g0/g1 read same addr
        uint2 b1 = sB[bt * 64 + 32 + n];
        union { half8 v; unsigned u[4]; } bu0, bu1;
        bu0.u[0] = b0.x; bu0.u[1] = b0.y; bu0.u[2] = c2; bu0.u[3] = 0u;
        bu1.u[0] = b1.x; bu1.u[1] = b1.y; bu1.u[2] = c2; bu1.u[3] = 0u;

        floatx16 d0 = __builtin_amdgcn_mfma_f32_32x32x16_f16(af, bu0.v, zacc, 0, 0, 0);
        floatx16 d1 = __builtin_amdgcn_mfma_f32_32x32x16_f16(af, bu1.v, zacc, 0, 0, 0);

#pragma unroll
        for (int r = 0; r < 16; ++r)
            rowmin[r] = fminf(fminf(rowmin[r], d0[r]), d1[r]);   // v_min3
    }

    // ---- epilogue: reduce across the 32 cols (xor-shuffle within n-group) ----
#pragma unroll
    for (int mask = 1; mask <= 16; mask <<= 1)
#pragma unroll
        for (int r = 0; r < 16; ++r)
            rowmin[r] = fminf(rowmin[r], __shfl_xor(rowmin[r], mask));

    if (n == 0) {
#pragma unroll
        for (int r = 0; r < 16; ++r) {
            int rr = wave * 32 + g * 4 + ((r & 3) + 8 * (r >> 2));   // C/D row map
            sRowMin[rr] = rowmin[r];
        }
    }
    __syncthreads();

    if (tid < ROWS) {   // one partial slot per (dir,row,ychunk) — no atomics
        int grow = blockIdx.x * ROWS + tid;
        if (grow < nA) pbase[(size_t)grow * YC + blockIdx.y] = sRowMin[tid];
    }
}

// Stage 1: per-row min over YC contiguous partials -> sqrt -> per-block sum
__global__ __launch_bounds__(256) void reduce1_kernel(
    const float* __restrict__ part, float* __restrict__ bsum,
    int n1, int n2, int YC)
{
    __shared__ float s[256];
    int r = blockIdx.x * 256 + threadIdx.x;
    float acc = 0.0f;
    int ntot = n1 + n2;
    if (r < ntot) {
        const float* p = part + (size_t)r * YC;
        float m = 1e30f;
        for (int y = 0; y < YC; ++y) m = fminf(m, p[y]);
        acc = sqrtf(fmaxf(m, 0.0f));
    }
    s[threadIdx.x] = acc;
    __syncthreads();
    for (int w = 128; w > 0; w >>= 1) {
        if (threadIdx.x < w) s[threadIdx.x] += s[threadIdx.x + w];
        __syncthreads();
    }
    if (threadIdx.x == 0) bsum[blockIdx.x] = s[0];
}

// Stage 2: sum the per-block sums -> out[0]
__global__ __launch_bounds__(256) void reduce2_kernel(
    const float* __restrict__ bsum, int nb, float* __restrict__ out)
{
    __shared__ float s[256];
    float acc = 0.0f;
    for (int i = threadIdx.x; i < nb; i += 256) acc += bsum[i];
    s[threadIdx.x] = acc;
    __syncthreads();
    for (int w = 128; w > 0; w >>= 1) {
        if (threadIdx.x < w) s[threadIdx.x] += s[threadIdx.x + w];
        __syncthreads();
    }
    if (threadIdx.x == 0) out[0] = s[0];
}

extern "C" void kernel_launch(void* const* d_in, const int* in_sizes, int n_in,
                              void* d_out, int out_size, void* d_ws, size_t ws_size,
                              hipStream_t stream) {
    const float* P1 = (const float*)d_in[0];
    const float* P2 = (const float*)d_in[1];
    const int n1 = in_sizes[0] / 3;   // 16384
    const int n2 = in_sizes[1] / 3;   // 16384
    const int nmax = (n1 > n2) ? n1 : n2;
    const int YC = (nmax + CH - 1) / CH;          // y-chunks (same grid both dirs)

    float* part = (float*)d_ws;                   // [(n1+n2) * YC] partial row-mins
    float* bsum = part + (size_t)YC * (n1 + n2);  // per-block sums
    float* out  = (float*)d_out;

    {   // two independent sweeps (z = direction), pure register row-mins
        dim3 grid((nmax + ROWS - 1) / ROWS, YC, 2);
        chamfer_sweep_kernel<<<grid, BLK, 0, stream>>>(P1, P2, part, n1, n2, YC);
    }
    int nb = (n1 + n2 + 255) / 256;
    reduce1_kernel<<<nb, 256, 0, stream>>>(part, bsum, n1, n2, YC);
    reduce2_kernel<<<1, 256, 0, stream>>>(bsum, nb, out);
}